// Round 5
// baseline (7342.912 us; speedup 1.0000x reference)
//
#include <hip/hip_runtime.h>

typedef _Float16 f16x8 __attribute__((ext_vector_type(8)));
typedef float f32x4 __attribute__((ext_vector_type(4)));

constexpr int S_ = 128;
constexpr float DT_ = 0.1f;
constexpr float LS = 2048.0f;          // lo-term scale (2^11) keeps fp16 lo parts normal
constexpr float INV = 1.0f / 2048.0f;

#define MFMA(a, b, c) __builtin_amdgcn_mfma_f32_16x16x32_f16((a), (b), (c), 0, 0, 0)

// bias LDS offsets (floats)
#define OB0   0
#define OB1   256
#define OB2   512
#define OBHH0 640
#define OBIH0 1024
#define OBIH1 1408
#define OBHH1 1792
#define NBIAS 2176

__device__ __forceinline__ float fast_tanh(float x) {
    float e = __expf(2.0f * x);
    return 1.0f - 2.0f / (e + 1.0f);
}
__device__ __forceinline__ float fast_sigmoid(float x) {
    return 1.0f / (1.0f + __expf(-x));
}

// fp32 row-major KxN -> fp16 hi/lo MFMA-B-fragment blobs.
// Tile (nt,kt) at ((nt*KT)+kt)*512; elem lane*8+j <-> B[kt*32+(lane>>4)*8+j][nt*16+(lane&15)].
__global__ void prep_hl(const float* __restrict__ src, _Float16* __restrict__ hi,
                        _Float16* __restrict__ lo, int K, int N) {
    int e = blockIdx.x * 256 + threadIdx.x;
    if (e >= K * N) return;
    int tile = e >> 9, r = e & 511;
    int lane = r >> 3, j = r & 7;
    int KT = K >> 5;
    int nt = tile / KT, kt = tile - nt * KT;
    int k = kt * 32 + ((lane >> 4) << 3) + j;
    int n = nt * 16 + (lane & 15);
    float v = src[k * N + n];
    _Float16 h = (_Float16)v;
    hi[e] = h;
    lo[e] = (_Float16)((v - (float)h) * LS);
}

__global__ __launch_bounds__(512) void odernn_mfma(
    const float* __restrict__ x2d, const int* __restrict__ maskp,
    const _Float16* __restrict__ w0h, const _Float16* __restrict__ w0l,
    const _Float16* __restrict__ w1hg, const _Float16* __restrict__ w1lg,
    const _Float16* __restrict__ w2h, const _Float16* __restrict__ w2l,
    const _Float16* __restrict__ hh0h, const _Float16* __restrict__ hh0l,
    const _Float16* __restrict__ ih1h, const _Float16* __restrict__ ih1l,
    const _Float16* __restrict__ hh1h, const _Float16* __restrict__ hh1l,
    const float* __restrict__ b0, const float* __restrict__ b1,
    const float* __restrict__ b2, const float* __restrict__ bhh0,
    const float* __restrict__ bih0, const float* __restrict__ wih0,
    const float* __restrict__ bih1, const float* __restrict__ bhh1,
    const float* __restrict__ wout, const float* __restrict__ bout,
    const float* __restrict__ h0, float* __restrict__ out)
{
    __shared__ float hF[16][128];                       // fp32 master hidden state
    __shared__ _Float16 bAh[16][264], bAl[16][264];     // t2 (256-wide) hi/lo
    __shared__ _Float16 bBh[16][264], bBl[16][264];     // t1 / h2 hi/lo
    __shared__ _Float16 bHh[16][136], bHl[16][136];     // current h / h1 hi/lo
    __shared__ float sbias[NBIAS];
    __shared__ float swi0[768];
    __shared__ float swout[384];
    __shared__ float sbout[4];
    __shared__ float sx0[16], sx1[16], smm[16];
    __shared__ int sIdx[16];

    const int tid = (int)threadIdx.x;
    const int wv = tid >> 6;            // wave 0..7
    const int l = tid & 63;
    const int lrow = l & 15;            // A-row / D-col within tile
    const int lk8 = (l >> 4) << 3;      // k-octet within 32-wide k-tile
    const int rbase = (l >> 4) << 2;    // D-row base for this lane

    // ---- LDS init ----
    for (int e = tid; e < 256; e += 512) { sbias[OB0 + e] = b0[e]; sbias[OB1 + e] = b1[e]; }
    for (int e = tid; e < 128; e += 512) sbias[OB2 + e] = b2[e];
    for (int e = tid; e < 384; e += 512) {
        sbias[OBHH0 + e] = bhh0[e];
        sbias[OBIH0 + e] = bih0[e];
        sbias[OBIH1 + e] = bih1[e];
        sbias[OBHH1 + e] = bhh1[e];
        swout[e] = wout[e];
    }
    for (int e = tid; e < 768; e += 512) swi0[e] = wih0[e];
    if (tid < 3) sbout[tid] = bout[tid];
    for (int e = tid; e < 2048; e += 512) {
        int row = e >> 7, col = e & 127;
        float v = h0[col];
        hF[row][col] = v;
        _Float16 hh = (_Float16)v;
        bHh[row][col] = hh;
        bHl[row][col] = (_Float16)((v - (float)hh) * LS);
    }
    if (tid < 16) {
        int grow = (int)blockIdx.x * 16 + tid;
        int bb = grow / 34, nn = grow - bb * 34;
        sIdx[tid] = bb * (S_ * 34) + nn;
    }
    __syncthreads();

    for (int s = 0; s < S_; ++s) {
        // x/mask for this step (consumed at P5, several barriers later)
        if (tid < 16) {
            int idx = sIdx[tid] + s * 34;
            float fm = (float)maskp[idx];
            smm[tid] = fm;
            sx0[tid] = x2d[2 * idx] * fm;
            sx1[tid] = x2d[2 * idx + 1] * fm;
        }

        // ================= 4 Euler steps =================
        for (int it = 0; it < 4; ++it) {
            // P1: t1 = tanh(h @ w0 + b0) -> bufB   (K=128 KT=4, NT=16: 2/wave)
            {
                const int n0 = wv << 4, n1 = (wv + 8) << 4;
                const f16x8* B0h = (const f16x8*)w0h + (size_t)(wv * 4) * 64 + l;
                const f16x8* B0l = (const f16x8*)w0l + (size_t)(wv * 4) * 64 + l;
                const f16x8* B1h = (const f16x8*)w0h + (size_t)((wv + 8) * 4) * 64 + l;
                const f16x8* B1l = (const f16x8*)w0l + (size_t)((wv + 8) * 4) * 64 + l;
                f16x8 bh0[4], bl0[4], bh1[4], bl1[4];
#pragma unroll
                for (int kt = 0; kt < 4; ++kt) {
                    bh0[kt] = B0h[kt * 64]; bl0[kt] = B0l[kt * 64];
                    bh1[kt] = B1h[kt * 64]; bl1[kt] = B1l[kt * 64];
                }
                float bv0 = sbias[OB0 + n0 + lrow], bv1 = sbias[OB0 + n1 + lrow];
                f32x4 a0 = {bv0, bv0, bv0, bv0}, a1 = {bv1, bv1, bv1, bv1};
                f32x4 p0 = {0, 0, 0, 0}, q0 = {0, 0, 0, 0}, p1 = {0, 0, 0, 0}, q1 = {0, 0, 0, 0};
#pragma unroll
                for (int kt = 0; kt < 4; ++kt) {
                    f16x8 ah = *(const f16x8*)&bHh[lrow][kt * 32 + lk8];
                    f16x8 al = *(const f16x8*)&bHl[lrow][kt * 32 + lk8];
                    a0 = MFMA(ah, bh0[kt], a0);
                    p0 = MFMA(ah, bl0[kt], p0);
                    q0 = MFMA(al, bh0[kt], q0);
                    a1 = MFMA(ah, bh1[kt], a1);
                    p1 = MFMA(ah, bl1[kt], p1);
                    q1 = MFMA(al, bh1[kt], q1);
                }
#pragma unroll
                for (int r = 0; r < 4; ++r) {
                    int row = rbase + r;
                    float v0 = fast_tanh(a0[r] + (p0[r] + q0[r]) * INV);
                    float v1 = fast_tanh(a1[r] + (p1[r] + q1[r]) * INV);
                    _Float16 hh = (_Float16)v0;
                    bBh[row][n0 + lrow] = hh;
                    bBl[row][n0 + lrow] = (_Float16)((v0 - (float)hh) * LS);
                    hh = (_Float16)v1;
                    bBh[row][n1 + lrow] = hh;
                    bBl[row][n1 + lrow] = (_Float16)((v1 - (float)hh) * LS);
                }
            }
            __syncthreads();

            // P2: t2 = tanh(t1 @ w1 + b1) -> bufA  (K=256 KT=8, NT=16: 2/wave)
            {
                const int n0 = wv << 4, n1 = (wv + 8) << 4;
                const f16x8* B0h = (const f16x8*)w1hg + (size_t)(wv * 8) * 64 + l;
                const f16x8* B0l = (const f16x8*)w1lg + (size_t)(wv * 8) * 64 + l;
                const f16x8* B1h = (const f16x8*)w1hg + (size_t)((wv + 8) * 8) * 64 + l;
                const f16x8* B1l = (const f16x8*)w1lg + (size_t)((wv + 8) * 8) * 64 + l;
                f16x8 bh0[8], bl0[8], bh1[8], bl1[8];
#pragma unroll
                for (int kt = 0; kt < 8; ++kt) {
                    bh0[kt] = B0h[kt * 64]; bl0[kt] = B0l[kt * 64];
                    bh1[kt] = B1h[kt * 64]; bl1[kt] = B1l[kt * 64];
                }
                float bv0 = sbias[OB1 + n0 + lrow], bv1 = sbias[OB1 + n1 + lrow];
                f32x4 a0 = {bv0, bv0, bv0, bv0}, a1 = {bv1, bv1, bv1, bv1};
                f32x4 p0 = {0, 0, 0, 0}, q0 = {0, 0, 0, 0}, p1 = {0, 0, 0, 0}, q1 = {0, 0, 0, 0};
#pragma unroll
                for (int kt = 0; kt < 8; ++kt) {
                    f16x8 ah = *(const f16x8*)&bBh[lrow][kt * 32 + lk8];
                    f16x8 al = *(const f16x8*)&bBl[lrow][kt * 32 + lk8];
                    a0 = MFMA(ah, bh0[kt], a0);
                    p0 = MFMA(ah, bl0[kt], p0);
                    q0 = MFMA(al, bh0[kt], q0);
                    a1 = MFMA(ah, bh1[kt], a1);
                    p1 = MFMA(ah, bl1[kt], p1);
                    q1 = MFMA(al, bh1[kt], q1);
                }
#pragma unroll
                for (int r = 0; r < 4; ++r) {
                    int row = rbase + r;
                    float v0 = fast_tanh(a0[r] + (p0[r] + q0[r]) * INV);
                    float v1 = fast_tanh(a1[r] + (p1[r] + q1[r]) * INV);
                    _Float16 hh = (_Float16)v0;
                    bAh[row][n0 + lrow] = hh;
                    bAl[row][n0 + lrow] = (_Float16)((v0 - (float)hh) * LS);
                    hh = (_Float16)v1;
                    bAh[row][n1 + lrow] = hh;
                    bAl[row][n1 + lrow] = (_Float16)((v1 - (float)hh) * LS);
                }
            }
            __syncthreads();

            // P3: f = t2 @ w2 + b2 ; hF += DT*f ; cast new h -> bufH  (K=256 KT=8, NT=8)
            {
                const int n0 = wv << 4;
                const f16x8* Bh = (const f16x8*)w2h + (size_t)(wv * 8) * 64 + l;
                const f16x8* Bl = (const f16x8*)w2l + (size_t)(wv * 8) * 64 + l;
                f16x8 bh[8], bl[8];
#pragma unroll
                for (int kt = 0; kt < 8; ++kt) { bh[kt] = Bh[kt * 64]; bl[kt] = Bl[kt * 64]; }
                float bv = sbias[OB2 + n0 + lrow];
                f32x4 acc = {bv, bv, bv, bv};
                f32x4 pp = {0, 0, 0, 0}, qq = {0, 0, 0, 0};
#pragma unroll
                for (int kt = 0; kt < 8; ++kt) {
                    f16x8 ah = *(const f16x8*)&bAh[lrow][kt * 32 + lk8];
                    f16x8 al = *(const f16x8*)&bAl[lrow][kt * 32 + lk8];
                    acc = MFMA(ah, bh[kt], acc);
                    pp = MFMA(ah, bl[kt], pp);
                    qq = MFMA(al, bh[kt], qq);
                }
#pragma unroll
                for (int r = 0; r < 4; ++r) {
                    int row = rbase + r, col = n0 + lrow;
                    float v = hF[row][col] + DT_ * (acc[r] + (pp[r] + qq[r]) * INV);
                    hF[row][col] = v;
                    _Float16 hh = (_Float16)v;
                    bHh[row][col] = hh;
                    bHl[row][col] = (_Float16)((v - (float)hh) * LS);
                }
            }
            __syncthreads();
        }

        // P5: gh0 = h1 @ whh0 + bhh0 (KT=4, NT=24: 3/wave) ; y-out ; GRU0 combine -> bufB
        {
            f16x8 bh[3][4], bl[3][4];
#pragma unroll
            for (int t = 0; t < 3; ++t) {
                const f16x8* Bh = (const f16x8*)hh0h + (size_t)((wv + (t << 3)) * 4) * 64 + l;
                const f16x8* Bl = (const f16x8*)hh0l + (size_t)((wv + (t << 3)) * 4) * 64 + l;
#pragma unroll
                for (int kt = 0; kt < 4; ++kt) { bh[t][kt] = Bh[kt * 64]; bl[t][kt] = Bl[kt * 64]; }
            }
            f32x4 acc0, acc1, acc2;
            f32x4 p0 = {0,0,0,0}, q0 = {0,0,0,0}, p1 = {0,0,0,0}, q1 = {0,0,0,0}, p2 = {0,0,0,0}, q2 = {0,0,0,0};
            {
                float v0 = sbias[OBHH0 + ((wv) << 4) + lrow];
                float v1 = sbias[OBHH0 + ((wv + 8) << 4) + lrow];
                float v2 = sbias[OBHH0 + ((wv + 16) << 4) + lrow];
                acc0 = (f32x4){v0, v0, v0, v0};
                acc1 = (f32x4){v1, v1, v1, v1};
                acc2 = (f32x4){v2, v2, v2, v2};
            }
#pragma unroll
            for (int kt = 0; kt < 4; ++kt) {
                f16x8 ah = *(const f16x8*)&bHh[lrow][kt * 32 + lk8];
                f16x8 al = *(const f16x8*)&bHl[lrow][kt * 32 + lk8];
                acc0 = MFMA(ah, bh[0][kt], acc0); p0 = MFMA(ah, bl[0][kt], p0); q0 = MFMA(al, bh[0][kt], q0);
                acc1 = MFMA(ah, bh[1][kt], acc1); p1 = MFMA(ah, bl[1][kt], p1); q1 = MFMA(al, bh[1][kt], q1);
                acc2 = MFMA(ah, bh[2][kt], acc2); p2 = MFMA(ah, bl[2][kt], p2); q2 = MFMA(al, bh[2][kt], q2);
            }
            // y = h1 @ wout + bout  (lanes 0-31: row wv ; lanes 32-63: row wv+8)
            {
                int yrow = wv + ((l >> 5) << 3);
                int ll = l & 31;
                int c0 = ll << 2;
                float4 hv = *(const float4*)&hF[yrow][c0];
                float y0 = hv.x * swout[c0 * 3] + hv.y * swout[(c0 + 1) * 3] +
                           hv.z * swout[(c0 + 2) * 3] + hv.w * swout[(c0 + 3) * 3];
                float y1 = hv.x * swout[c0 * 3 + 1] + hv.y * swout[(c0 + 1) * 3 + 1] +
                           hv.z * swout[(c0 + 2) * 3 + 1] + hv.w * swout[(c0 + 3) * 3 + 1];
                float y2 = hv.x * swout[c0 * 3 + 2] + hv.y * swout[(c0 + 1) * 3 + 2] +
                           hv.z * swout[(c0 + 2) * 3 + 2] + hv.w * swout[(c0 + 3) * 3 + 2];
#pragma unroll
                for (int m = 16; m >= 1; m >>= 1) {
                    y0 += __shfl_xor(y0, m, 64);
                    y1 += __shfl_xor(y1, m, 64);
                    y2 += __shfl_xor(y2, m, 64);
                }
                if (ll == 0) {
                    int idx = sIdx[yrow] + s * 34;
                    out[idx * 3 + 0] = y0 + sbout[0];
                    out[idx * 3 + 1] = y1 + sbout[1];
                    out[idx * 3 + 2] = y2 + sbout[2];
                }
            }
            // GRU0 combine: h2 -> bufB cols 0..127
            {
                int col = (wv << 4) + lrow;
                float wxr0 = swi0[col], wxr1 = swi0[384 + col];
                float wxz0 = swi0[128 + col], wxz1 = swi0[384 + 128 + col];
                float wxn0 = swi0[256 + col], wxn1 = swi0[384 + 256 + col];
                float bir = sbias[OBIH0 + col], biz = sbias[OBIH0 + 128 + col], bin = sbias[OBIH0 + 256 + col];
#pragma unroll
                for (int r = 0; r < 4; ++r) {
                    int row = rbase + r;
                    float ghr = acc0[r] + (p0[r] + q0[r]) * INV;
                    float ghz = acc1[r] + (p1[r] + q1[r]) * INV;
                    float ghn = acc2[r] + (p2[r] + q2[r]) * INV;
                    float xa = sx0[row], xb = sx1[row];
                    float rg = fast_sigmoid(bir + xa * wxr0 + xb * wxr1 + ghr);
                    float zg = fast_sigmoid(biz + xa * wxz0 + xb * wxz1 + ghz);
                    float nn = fast_tanh(bin + xa * wxn0 + xb * wxn1 + rg * ghn);
                    float h1 = hF[row][col];
                    float h2 = (1.0f - zg) * nn + zg * h1;
                    _Float16 hh = (_Float16)h2;
                    bBh[row][col] = hh;
                    bBl[row][col] = (_Float16)((h2 - (float)hh) * LS);
                }
            }
        }
        __syncthreads();

        // P7: gi1 = h2 @ wih1 + bih1 ; gh1 = h1 @ whh1 + bhh1 ; GRU1 combine -> hF + bufH
        {
            f32x4 gi0, gi1, gi2;
            {
                f16x8 bh[3][4], bl[3][4];
#pragma unroll
                for (int t = 0; t < 3; ++t) {
                    const f16x8* Bh = (const f16x8*)ih1h + (size_t)((wv + (t << 3)) * 4) * 64 + l;
                    const f16x8* Bl = (const f16x8*)ih1l + (size_t)((wv + (t << 3)) * 4) * 64 + l;
#pragma unroll
                    for (int kt = 0; kt < 4; ++kt) { bh[t][kt] = Bh[kt * 64]; bl[t][kt] = Bl[kt * 64]; }
                }
                f32x4 a0, a1, a2;
                f32x4 p0 = {0,0,0,0}, q0 = {0,0,0,0}, p1 = {0,0,0,0}, q1 = {0,0,0,0}, p2 = {0,0,0,0}, q2 = {0,0,0,0};
                {
                    float v0 = sbias[OBIH1 + ((wv) << 4) + lrow];
                    float v1 = sbias[OBIH1 + ((wv + 8) << 4) + lrow];
                    float v2 = sbias[OBIH1 + ((wv + 16) << 4) + lrow];
                    a0 = (f32x4){v0, v0, v0, v0};
                    a1 = (f32x4){v1, v1, v1, v1};
                    a2 = (f32x4){v2, v2, v2, v2};
                }
#pragma unroll
                for (int kt = 0; kt < 4; ++kt) {
                    f16x8 ah = *(const f16x8*)&bBh[lrow][kt * 32 + lk8];
                    f16x8 al = *(const f16x8*)&bBl[lrow][kt * 32 + lk8];
                    a0 = MFMA(ah, bh[0][kt], a0); p0 = MFMA(ah, bl[0][kt], p0); q0 = MFMA(al, bh[0][kt], q0);
                    a1 = MFMA(ah, bh[1][kt], a1); p1 = MFMA(ah, bl[1][kt], p1); q1 = MFMA(al, bh[1][kt], q1);
                    a2 = MFMA(ah, bh[2][kt], a2); p2 = MFMA(ah, bl[2][kt], p2); q2 = MFMA(al, bh[2][kt], q2);
                }
                gi0 = a0 + (p0 + q0) * INV;
                gi1 = a1 + (p1 + q1) * INV;
                gi2 = a2 + (p2 + q2) * INV;
            }

            f32x4 aH0, aH1, aH2;
            f32x4 pH0 = {0,0,0,0}, qH0 = {0,0,0,0}, pH1 = {0,0,0,0}, qH1 = {0,0,0,0}, pH2 = {0,0,0,0}, qH2 = {0,0,0,0};
            {
                f16x8 bh[3][4], bl[3][4];
#pragma unroll
                for (int t = 0; t < 3; ++t) {
                    const f16x8* Bh = (const f16x8*)hh1h + (size_t)((wv + (t << 3)) * 4) * 64 + l;
                    const f16x8* Bl = (const f16x8*)hh1l + (size_t)((wv + (t << 3)) * 4) * 64 + l;
#pragma unroll
                    for (int kt = 0; kt < 4; ++kt) { bh[t][kt] = Bh[kt * 64]; bl[t][kt] = Bl[kt * 64]; }
                }
                {
                    float v0 = sbias[OBHH1 + ((wv) << 4) + lrow];
                    float v1 = sbias[OBHH1 + ((wv + 8) << 4) + lrow];
                    float v2 = sbias[OBHH1 + ((wv + 16) << 4) + lrow];
                    aH0 = (f32x4){v0, v0, v0, v0};
                    aH1 = (f32x4){v1, v1, v1, v1};
                    aH2 = (f32x4){v2, v2, v2, v2};
                }
#pragma unroll
                for (int kt = 0; kt < 4; ++kt) {
                    f16x8 ah = *(const f16x8*)&bHh[lrow][kt * 32 + lk8];
                    f16x8 al = *(const f16x8*)&bHl[lrow][kt * 32 + lk8];
                    aH0 = MFMA(ah, bh[0][kt], aH0); pH0 = MFMA(ah, bl[0][kt], pH0); qH0 = MFMA(al, bh[0][kt], qH0);
                    aH1 = MFMA(ah, bh[1][kt], aH1); pH1 = MFMA(ah, bl[1][kt], pH1); qH1 = MFMA(al, bh[1][kt], qH1);
                    aH2 = MFMA(ah, bh[2][kt], aH2); pH2 = MFMA(ah, bl[2][kt], pH2); qH2 = MFMA(al, bh[2][kt], qH2);
                }
            }
            __syncthreads();   // all reads of bHh/bHl for this step are done
#pragma unroll
            for (int r = 0; r < 4; ++r) {
                int row = rbase + r, col = (wv << 4) + lrow;
                float ghr = aH0[r] + (pH0[r] + qH0[r]) * INV;
                float ghz = aH1[r] + (pH1[r] + qH1[r]) * INV;
                float ghn = aH2[r] + (pH2[r] + qH2[r]) * INV;
                float rg = fast_sigmoid(gi0[r] + ghr);
                float zg = fast_sigmoid(gi1[r] + ghz);
                float nn = fast_tanh(gi2[r] + rg * ghn);
                float h1 = hF[row][col];
                float h2 = (1.0f - zg) * nn + zg * h1;
                float v = (smm[row] != 0.0f) ? h2 : h1;
                hF[row][col] = v;
                _Float16 hh = (_Float16)v;
                bHh[row][col] = hh;
                bHl[row][col] = (_Float16)((v - (float)hh) * LS);
            }
        }
        __syncthreads();
    }
}

extern "C" void kernel_launch(void* const* d_in, const int* in_sizes, int n_in,
                              void* d_out, int out_size, void* d_ws, size_t ws_size,
                              hipStream_t stream) {
    const float* x2d  = (const float*)d_in[0];
    const int*   mask = (const int*)d_in[1];
    const float* w0   = (const float*)d_in[2];
    const float* b0   = (const float*)d_in[3];
    const float* w1   = (const float*)d_in[4];
    const float* b1   = (const float*)d_in[5];
    const float* w2   = (const float*)d_in[6];
    const float* b2   = (const float*)d_in[7];
    const float* wih0 = (const float*)d_in[8];
    const float* whh0 = (const float*)d_in[9];
    const float* bih0 = (const float*)d_in[10];
    const float* bhh0 = (const float*)d_in[11];
    const float* wih1 = (const float*)d_in[12];
    const float* whh1 = (const float*)d_in[13];
    const float* bih1 = (const float*)d_in[14];
    const float* bhh1 = (const float*)d_in[15];
    const float* wout = (const float*)d_in[16];
    const float* bout = (const float*)d_in[17];
    const float* h0   = (const float*)d_in[18];
    float* out = (float*)d_out;

    _Float16* base = (_Float16*)d_ws;
    _Float16* pw0h  = base;                 // 32768
    _Float16* pw1h  = base + 32768;         // 65536
    _Float16* pw2h  = base + 98304;         // 32768
    _Float16* ph0h  = base + 131072;        // 49152 (whh0)
    _Float16* pi1h  = base + 180224;        // 49152 (wih1)
    _Float16* ph1h  = base + 229376;        // 49152 (whh1)
    _Float16* lobase = base + 278528;
    _Float16* pw0l  = lobase;
    _Float16* pw1l  = lobase + 32768;
    _Float16* pw2l  = lobase + 98304;
    _Float16* ph0l  = lobase + 131072;
    _Float16* pi1l  = lobase + 180224;
    _Float16* ph1l  = lobase + 229376;

    hipLaunchKernelGGL(prep_hl, dim3(128), dim3(256), 0, stream, w0,   pw0h, pw0l, 128, 256);
    hipLaunchKernelGGL(prep_hl, dim3(256), dim3(256), 0, stream, w1,   pw1h, pw1l, 256, 256);
    hipLaunchKernelGGL(prep_hl, dim3(128), dim3(256), 0, stream, w2,   pw2h, pw2l, 256, 128);
    hipLaunchKernelGGL(prep_hl, dim3(192), dim3(256), 0, stream, whh0, ph0h, ph0l, 128, 384);
    hipLaunchKernelGGL(prep_hl, dim3(192), dim3(256), 0, stream, wih1, pi1h, pi1l, 128, 384);
    hipLaunchKernelGGL(prep_hl, dim3(192), dim3(256), 0, stream, whh1, ph1h, ph1l, 128, 384);

    hipLaunchKernelGGL(odernn_mfma, dim3(68), dim3(512), 0, stream,
        x2d, mask, pw0h, pw0l, pw1h, pw1l, pw2h, pw2l,
        ph0h, ph0l, pi1h, pi1l, ph1h, ph1l,
        b0, b1, b2, bhh0, bih0, wih0, bih1, bhh1, wout, bout, h0, out);
}

// Round 6
// 7217.488 us; speedup vs baseline: 1.0174x; 1.0174x over previous
//
#include <hip/hip_runtime.h>

typedef _Float16 f16x8 __attribute__((ext_vector_type(8)));
typedef float f32x4 __attribute__((ext_vector_type(4)));

constexpr int S_ = 128;
constexpr float DT_ = 0.1f;
constexpr float LS = 2048.0f;          // lo-term scale (2^11) keeps fp16 lo parts normal
constexpr float INV = 1.0f / 2048.0f;

#define MFMA(a, b, c) __builtin_amdgcn_mfma_f32_16x16x32_f16((a), (b), (c), 0, 0, 0)

// bias LDS offsets (floats)
#define OB0   0
#define OB1   256
#define OB2   512
#define OBHH0 640
#define OBIH0 1024
#define OBIH1 1408
#define OBHH1 1792
#define NBIAS 2176

__device__ __forceinline__ float fast_tanh(float x) {
    float e = __expf(2.0f * x);
    return 1.0f - 2.0f / (e + 1.0f);
}
__device__ __forceinline__ float fast_sigmoid(float x) {
    return 1.0f / (1.0f + __expf(-x));
}

// One 16-col n-tile x (KT*32)-deep K: gather fp32 weights straight from d_in
// (row-major KxN, L2-cacheable), split to fp16 hi/lo in regs, MFMA 3-term.
// acc += Ah*Bh ; pe += Ah*Bl ; qe += Al*Bh   (caller combines acc + (pe+qe)*INV)
template<int KT>
__device__ __forceinline__ void wtile_mm(
    const float* __restrict__ W, int N, int nt,
    const _Float16* __restrict__ Ah, const _Float16* __restrict__ Al, int lda,
    int lrow, int lk8, f32x4& acc, f32x4& pe, f32x4& qe)
{
    const float* base = W + (size_t)lk8 * N + nt * 16 + lrow;
    float raw[KT][8];
#pragma unroll
    for (int kt = 0; kt < KT; ++kt)
#pragma unroll
        for (int j = 0; j < 8; ++j)
            raw[kt][j] = base[(kt * 32 + j) * (size_t)N];
#pragma unroll
    for (int kt = 0; kt < KT; ++kt) {
        f16x8 bh, bl;
#pragma unroll
        for (int j = 0; j < 8; ++j) {
            float v = raw[kt][j];
            _Float16 h = (_Float16)v;
            bh[j] = h;
            bl[j] = (_Float16)((v - (float)h) * LS);
        }
        f16x8 ah = *(const f16x8*)(Ah + lrow * lda + kt * 32 + lk8);
        f16x8 al = *(const f16x8*)(Al + lrow * lda + kt * 32 + lk8);
        acc = MFMA(ah, bh, acc);
        pe  = MFMA(ah, bl, pe);
        qe  = MFMA(al, bh, qe);
    }
}

__global__ __launch_bounds__(512, 2) void odernn_mfma(
    const float* __restrict__ x2d, const int* __restrict__ maskp,
    const float* __restrict__ w0, const float* __restrict__ b0,
    const float* __restrict__ w1, const float* __restrict__ b1,
    const float* __restrict__ w2, const float* __restrict__ b2,
    const float* __restrict__ wih0, const float* __restrict__ whh0,
    const float* __restrict__ bih0, const float* __restrict__ bhh0,
    const float* __restrict__ wih1, const float* __restrict__ whh1,
    const float* __restrict__ bih1, const float* __restrict__ bhh1,
    const float* __restrict__ wout, const float* __restrict__ bout,
    const float* __restrict__ h0, float* __restrict__ out)
{
    __shared__ float hF[16][128];                       // fp32 master hidden state
    __shared__ _Float16 bAh[16][264], bAl[16][264];     // t2 (256-wide) hi/lo
    __shared__ _Float16 bBh[16][264], bBl[16][264];     // t1 / h2 hi/lo
    __shared__ _Float16 bHh[16][136], bHl[16][136];     // current h / h1 hi/lo
    __shared__ float sbias[NBIAS];
    __shared__ float swi0[768];
    __shared__ float swout[384];
    __shared__ float sbout[4];
    __shared__ float sx0[16], sx1[16], smm[16];
    __shared__ int sIdx[16];

    const int tid = (int)threadIdx.x;
    const int wv = tid >> 6;            // wave 0..7
    const int l = tid & 63;
    const int lrow = l & 15;            // A-row / D-col within tile
    const int lk8 = (l >> 4) << 3;      // k-octet within 32-wide k-tile
    const int rbase = (l >> 4) << 2;    // D-row base for this lane

    // ---- LDS init ----
    for (int e = tid; e < 256; e += 512) { sbias[OB0 + e] = b0[e]; sbias[OB1 + e] = b1[e]; }
    for (int e = tid; e < 128; e += 512) sbias[OB2 + e] = b2[e];
    for (int e = tid; e < 384; e += 512) {
        sbias[OBHH0 + e] = bhh0[e];
        sbias[OBIH0 + e] = bih0[e];
        sbias[OBIH1 + e] = bih1[e];
        sbias[OBHH1 + e] = bhh1[e];
        swout[e] = wout[e];
    }
    for (int e = tid; e < 768; e += 512) swi0[e] = wih0[e];
    if (tid < 3) sbout[tid] = bout[tid];
    for (int e = tid; e < 2048; e += 512) {
        int row = e >> 7, col = e & 127;
        float v = h0[col];
        hF[row][col] = v;
        _Float16 hh = (_Float16)v;
        bHh[row][col] = hh;
        bHl[row][col] = (_Float16)((v - (float)hh) * LS);
    }
    if (tid < 16) {
        int grow = (int)blockIdx.x * 16 + tid;
        int bb = grow / 34, nn = grow - bb * 34;
        sIdx[tid] = bb * (S_ * 34) + nn;
    }
    __syncthreads();

    for (int s = 0; s < S_; ++s) {
        // x/mask for this step (consumed at P5, several barriers later)
        if (tid < 16) {
            int idx = sIdx[tid] + s * 34;
            float fm = (float)maskp[idx];
            smm[tid] = fm;
            sx0[tid] = x2d[2 * idx] * fm;
            sx1[tid] = x2d[2 * idx + 1] * fm;
        }

        // ================= 4 Euler steps =================
        for (int it = 0; it < 4; ++it) {
            // P1: t1 = tanh(h @ w0 + b0) -> bufB   (K=128 KT=4, NT=16: 2/wave)
            {
                const int n0 = wv << 4, n1 = (wv + 8) << 4;
                float bv0 = sbias[OB0 + n0 + lrow], bv1 = sbias[OB0 + n1 + lrow];
                f32x4 a0 = {bv0, bv0, bv0, bv0}, a1 = {bv1, bv1, bv1, bv1};
                f32x4 p0 = {0, 0, 0, 0}, q0 = {0, 0, 0, 0}, p1 = {0, 0, 0, 0}, q1 = {0, 0, 0, 0};
                wtile_mm<4>(w0, 256, wv,     &bHh[0][0], &bHl[0][0], 136, lrow, lk8, a0, p0, q0);
                wtile_mm<4>(w0, 256, wv + 8, &bHh[0][0], &bHl[0][0], 136, lrow, lk8, a1, p1, q1);
#pragma unroll
                for (int r = 0; r < 4; ++r) {
                    int row = rbase + r;
                    float v0 = fast_tanh(a0[r] + (p0[r] + q0[r]) * INV);
                    float v1 = fast_tanh(a1[r] + (p1[r] + q1[r]) * INV);
                    _Float16 hh = (_Float16)v0;
                    bBh[row][n0 + lrow] = hh;
                    bBl[row][n0 + lrow] = (_Float16)((v0 - (float)hh) * LS);
                    hh = (_Float16)v1;
                    bBh[row][n1 + lrow] = hh;
                    bBl[row][n1 + lrow] = (_Float16)((v1 - (float)hh) * LS);
                }
            }
            __syncthreads();

            // P2: t2 = tanh(t1 @ w1 + b1) -> bufA  (K=256 KT=8, NT=16: 2/wave)
            {
                const int n0 = wv << 4, n1 = (wv + 8) << 4;
                float bv0 = sbias[OB1 + n0 + lrow], bv1 = sbias[OB1 + n1 + lrow];
                f32x4 a0 = {bv0, bv0, bv0, bv0}, a1 = {bv1, bv1, bv1, bv1};
                f32x4 p0 = {0, 0, 0, 0}, q0 = {0, 0, 0, 0}, p1 = {0, 0, 0, 0}, q1 = {0, 0, 0, 0};
                wtile_mm<8>(w1, 256, wv,     &bBh[0][0], &bBl[0][0], 264, lrow, lk8, a0, p0, q0);
                wtile_mm<8>(w1, 256, wv + 8, &bBh[0][0], &bBl[0][0], 264, lrow, lk8, a1, p1, q1);
#pragma unroll
                for (int r = 0; r < 4; ++r) {
                    int row = rbase + r;
                    float v0 = fast_tanh(a0[r] + (p0[r] + q0[r]) * INV);
                    float v1 = fast_tanh(a1[r] + (p1[r] + q1[r]) * INV);
                    _Float16 hh = (_Float16)v0;
                    bAh[row][n0 + lrow] = hh;
                    bAl[row][n0 + lrow] = (_Float16)((v0 - (float)hh) * LS);
                    hh = (_Float16)v1;
                    bAh[row][n1 + lrow] = hh;
                    bAl[row][n1 + lrow] = (_Float16)((v1 - (float)hh) * LS);
                }
            }
            __syncthreads();

            // P3: f = t2 @ w2 + b2 ; hF += DT*f ; cast new h -> bufH  (K=256 KT=8, NT=8)
            {
                const int n0 = wv << 4;
                float bv = sbias[OB2 + n0 + lrow];
                f32x4 acc = {bv, bv, bv, bv};
                f32x4 pp = {0, 0, 0, 0}, qq = {0, 0, 0, 0};
                wtile_mm<8>(w2, 128, wv, &bAh[0][0], &bAl[0][0], 264, lrow, lk8, acc, pp, qq);
#pragma unroll
                for (int r = 0; r < 4; ++r) {
                    int row = rbase + r, col = n0 + lrow;
                    float v = hF[row][col] + DT_ * (acc[r] + (pp[r] + qq[r]) * INV);
                    hF[row][col] = v;
                    _Float16 hh = (_Float16)v;
                    bHh[row][col] = hh;
                    bHl[row][col] = (_Float16)((v - (float)hh) * LS);
                }
            }
            __syncthreads();
        }

        // P5: gh0 = h1 @ whh0 + bhh0 (KT=4, NT=24: 3/wave) ; y-out ; GRU0 combine -> bufB
        {
            f32x4 acc0, acc1, acc2;
            f32x4 p0 = {0,0,0,0}, q0 = {0,0,0,0}, p1 = {0,0,0,0}, q1 = {0,0,0,0}, p2 = {0,0,0,0}, q2 = {0,0,0,0};
            {
                float v0 = sbias[OBHH0 + ((wv) << 4) + lrow];
                float v1 = sbias[OBHH0 + ((wv + 8) << 4) + lrow];
                float v2 = sbias[OBHH0 + ((wv + 16) << 4) + lrow];
                acc0 = (f32x4){v0, v0, v0, v0};
                acc1 = (f32x4){v1, v1, v1, v1};
                acc2 = (f32x4){v2, v2, v2, v2};
            }
            wtile_mm<4>(whh0, 384, wv,      &bHh[0][0], &bHl[0][0], 136, lrow, lk8, acc0, p0, q0);
            wtile_mm<4>(whh0, 384, wv + 8,  &bHh[0][0], &bHl[0][0], 136, lrow, lk8, acc1, p1, q1);
            wtile_mm<4>(whh0, 384, wv + 16, &bHh[0][0], &bHl[0][0], 136, lrow, lk8, acc2, p2, q2);
            // y = h1 @ wout + bout  (lanes 0-31: row wv ; lanes 32-63: row wv+8)
            {
                int yrow = wv + ((l >> 5) << 3);
                int ll = l & 31;
                int c0 = ll << 2;
                float4 hv = *(const float4*)&hF[yrow][c0];
                float y0 = hv.x * swout[c0 * 3] + hv.y * swout[(c0 + 1) * 3] +
                           hv.z * swout[(c0 + 2) * 3] + hv.w * swout[(c0 + 3) * 3];
                float y1 = hv.x * swout[c0 * 3 + 1] + hv.y * swout[(c0 + 1) * 3 + 1] +
                           hv.z * swout[(c0 + 2) * 3 + 1] + hv.w * swout[(c0 + 3) * 3 + 1];
                float y2 = hv.x * swout[c0 * 3 + 2] + hv.y * swout[(c0 + 1) * 3 + 2] +
                           hv.z * swout[(c0 + 2) * 3 + 2] + hv.w * swout[(c0 + 3) * 3 + 2];
#pragma unroll
                for (int m = 16; m >= 1; m >>= 1) {
                    y0 += __shfl_xor(y0, m, 64);
                    y1 += __shfl_xor(y1, m, 64);
                    y2 += __shfl_xor(y2, m, 64);
                }
                if (ll == 0) {
                    int idx = sIdx[yrow] + s * 34;
                    out[idx * 3 + 0] = y0 + sbout[0];
                    out[idx * 3 + 1] = y1 + sbout[1];
                    out[idx * 3 + 2] = y2 + sbout[2];
                }
            }
            // GRU0 combine: h2 -> bufB cols 0..127
            {
                int col = (wv << 4) + lrow;
                float wxr0 = swi0[col], wxr1 = swi0[384 + col];
                float wxz0 = swi0[128 + col], wxz1 = swi0[384 + 128 + col];
                float wxn0 = swi0[256 + col], wxn1 = swi0[384 + 256 + col];
                float bir = sbias[OBIH0 + col], biz = sbias[OBIH0 + 128 + col], bin = sbias[OBIH0 + 256 + col];
#pragma unroll
                for (int r = 0; r < 4; ++r) {
                    int row = rbase + r;
                    float ghr = acc0[r] + (p0[r] + q0[r]) * INV;
                    float ghz = acc1[r] + (p1[r] + q1[r]) * INV;
                    float ghn = acc2[r] + (p2[r] + q2[r]) * INV;
                    float xa = sx0[row], xb = sx1[row];
                    float rg = fast_sigmoid(bir + xa * wxr0 + xb * wxr1 + ghr);
                    float zg = fast_sigmoid(biz + xa * wxz0 + xb * wxz1 + ghz);
                    float nn = fast_tanh(bin + xa * wxn0 + xb * wxn1 + rg * ghn);
                    float h1 = hF[row][col];
                    float h2 = (1.0f - zg) * nn + zg * h1;
                    _Float16 hh = (_Float16)h2;
                    bBh[row][col] = hh;
                    bBl[row][col] = (_Float16)((h2 - (float)hh) * LS);
                }
            }
        }
        __syncthreads();

        // P7: gi1 = h2 @ wih1 + bih1 ; gh1 = h1 @ whh1 + bhh1 ; GRU1 combine -> hF + bufH
        {
            f32x4 gi0, gi1, gi2;
            {
                f32x4 a0, a1, a2;
                f32x4 p0 = {0,0,0,0}, q0 = {0,0,0,0}, p1 = {0,0,0,0}, q1 = {0,0,0,0}, p2 = {0,0,0,0}, q2 = {0,0,0,0};
                {
                    float v0 = sbias[OBIH1 + ((wv) << 4) + lrow];
                    float v1 = sbias[OBIH1 + ((wv + 8) << 4) + lrow];
                    float v2 = sbias[OBIH1 + ((wv + 16) << 4) + lrow];
                    a0 = (f32x4){v0, v0, v0, v0};
                    a1 = (f32x4){v1, v1, v1, v1};
                    a2 = (f32x4){v2, v2, v2, v2};
                }
                wtile_mm<4>(wih1, 384, wv,      &bBh[0][0], &bBl[0][0], 264, lrow, lk8, a0, p0, q0);
                wtile_mm<4>(wih1, 384, wv + 8,  &bBh[0][0], &bBl[0][0], 264, lrow, lk8, a1, p1, q1);
                wtile_mm<4>(wih1, 384, wv + 16, &bBh[0][0], &bBl[0][0], 264, lrow, lk8, a2, p2, q2);
                gi0 = a0 + (p0 + q0) * INV;
                gi1 = a1 + (p1 + q1) * INV;
                gi2 = a2 + (p2 + q2) * INV;
            }

            f32x4 aH0, aH1, aH2;
            f32x4 pH0 = {0,0,0,0}, qH0 = {0,0,0,0}, pH1 = {0,0,0,0}, qH1 = {0,0,0,0}, pH2 = {0,0,0,0}, qH2 = {0,0,0,0};
            {
                float v0 = sbias[OBHH1 + ((wv) << 4) + lrow];
                float v1 = sbias[OBHH1 + ((wv + 8) << 4) + lrow];
                float v2 = sbias[OBHH1 + ((wv + 16) << 4) + lrow];
                aH0 = (f32x4){v0, v0, v0, v0};
                aH1 = (f32x4){v1, v1, v1, v1};
                aH2 = (f32x4){v2, v2, v2, v2};
            }
            wtile_mm<4>(whh1, 384, wv,      &bHh[0][0], &bHl[0][0], 136, lrow, lk8, aH0, pH0, qH0);
            wtile_mm<4>(whh1, 384, wv + 8,  &bHh[0][0], &bHl[0][0], 136, lrow, lk8, aH1, pH1, qH1);
            wtile_mm<4>(whh1, 384, wv + 16, &bHh[0][0], &bHl[0][0], 136, lrow, lk8, aH2, pH2, qH2);

            __syncthreads();   // all reads of bHh/bHl for this step are done
#pragma unroll
            for (int r = 0; r < 4; ++r) {
                int row = rbase + r, col = (wv << 4) + lrow;
                float ghr = aH0[r] + (pH0[r] + qH0[r]) * INV;
                float ghz = aH1[r] + (pH1[r] + qH1[r]) * INV;
                float ghn = aH2[r] + (pH2[r] + qH2[r]) * INV;
                float rg = fast_sigmoid(gi0[r] + ghr);
                float zg = fast_sigmoid(gi1[r] + ghz);
                float nn = fast_tanh(gi2[r] + rg * ghn);
                float h1 = hF[row][col];
                float h2 = (1.0f - zg) * nn + zg * h1;
                float v = (smm[row] != 0.0f) ? h2 : h1;
                hF[row][col] = v;
                _Float16 hh = (_Float16)v;
                bHh[row][col] = hh;
                bHl[row][col] = (_Float16)((v - (float)hh) * LS);
            }
        }
        __syncthreads();
    }
}

extern "C" void kernel_launch(void* const* d_in, const int* in_sizes, int n_in,
                              void* d_out, int out_size, void* d_ws, size_t ws_size,
                              hipStream_t stream) {
    const float* x2d  = (const float*)d_in[0];
    const int*   mask = (const int*)d_in[1];
    const float* w0   = (const float*)d_in[2];
    const float* b0   = (const float*)d_in[3];
    const float* w1   = (const float*)d_in[4];
    const float* b1   = (const float*)d_in[5];
    const float* w2   = (const float*)d_in[6];
    const float* b2   = (const float*)d_in[7];
    const float* wih0 = (const float*)d_in[8];
    const float* whh0 = (const float*)d_in[9];
    const float* bih0 = (const float*)d_in[10];
    const float* bhh0 = (const float*)d_in[11];
    const float* wih1 = (const float*)d_in[12];
    const float* whh1 = (const float*)d_in[13];
    const float* bih1 = (const float*)d_in[14];
    const float* bhh1 = (const float*)d_in[15];
    const float* wout = (const float*)d_in[16];
    const float* bout = (const float*)d_in[17];
    const float* h0   = (const float*)d_in[18];
    float* out = (float*)d_out;

    hipLaunchKernelGGL(odernn_mfma, dim3(68), dim3(512), 0, stream,
        x2d, mask, w0, b0, w1, b1, w2, b2,
        wih0, whh0, bih0, bhh0, wih1, whh1, bih1, bhh1,
        wout, bout, h0, out);
}

// Round 8
// 6894.637 us; speedup vs baseline: 1.0650x; 1.0468x over previous
//
#include <hip/hip_runtime.h>

typedef _Float16 f16x8 __attribute__((ext_vector_type(8)));
typedef float f32x4 __attribute__((ext_vector_type(4)));

constexpr int S_ = 128;
constexpr float DT_ = 0.1f;
constexpr float LS = 2048.0f;          // lo-term scale (2^11) keeps fp16 lo parts normal
constexpr float INV = 1.0f / 2048.0f;

#define MFMA(a, b, c) __builtin_amdgcn_mfma_f32_16x16x32_f16((a), (b), (c), 0, 0, 0)

// bias LDS offsets (floats)
#define OB0   0
#define OB1   256
#define OB2   512
#define OBHH0 640
#define OBIH0 1024
#define OBIH1 1408
#define OBHH1 1792
#define NBIAS 2176

__device__ __forceinline__ float fast_tanh(float x) {
    float e = __expf(2.0f * x);
    return 1.0f - 2.0f / (e + 1.0f);
}
__device__ __forceinline__ float fast_sigmoid(float x) {
    return 1.0f / (1.0f + __expf(-x));
}
__device__ __forceinline__ f32x4 bc4(float v) { return (f32x4){v, v, v, v}; }

// fp32 row-major KxN -> fp16 hi/lo MFMA-B-fragment blobs.
// Tile (nt,kt) at ((nt*KT)+kt)*512; elem lane*8+j <-> B[kt*32+(lane>>4)*8+j][nt*16+(lane&15)].
__global__ void prep_hl(const float* __restrict__ src, _Float16* __restrict__ hi,
                        _Float16* __restrict__ lo, int K, int N) {
    int e = blockIdx.x * 256 + threadIdx.x;
    if (e >= K * N) return;
    int tile = e >> 9, r = e & 511;
    int lane = r >> 3, j = r & 7;
    int KT = K >> 5;
    int nt = tile / KT, kt = tile - nt * KT;
    int k = kt * 32 + ((lane >> 4) << 3) + j;
    int n = nt * 16 + (lane & 15);
    float v = src[k * N + n];
    _Float16 h = (_Float16)v;
    hi[e] = h;
    lo[e] = (_Float16)((v - (float)h) * LS);
}

// One full 16-col n-tile: load 2*KT B-fragments (hi/lo), run 3*KT MFMAs,
// return combined f32x4 = acc + (pe+qe)/LS. Small per-tile register footprint
// (KT=8: 64 VGPR fragments + 12 acc) -- the R4 multi-tile arrays spilled.
template<int KT>
__device__ __forceinline__ f32x4 tile_mm(
    const _Float16* __restrict__ Wh, const _Float16* __restrict__ Wl, int nt,
    const _Float16* __restrict__ Ah, const _Float16* __restrict__ Al, int lda,
    int l, int lrow, int lk8, float bias)
{
    const _Float16* ph = Wh + ((size_t)nt * KT) * 512 + l * 8;
    const _Float16* pl = Wl + ((size_t)nt * KT) * 512 + l * 8;
    f16x8 bh[KT], bl[KT];
#pragma unroll
    for (int kt = 0; kt < KT; ++kt) {
        bh[kt] = *(const f16x8*)(ph + kt * 512);
        bl[kt] = *(const f16x8*)(pl + kt * 512);
    }
    f32x4 acc = bc4(bias), pe = bc4(0.f), qe = bc4(0.f);
#pragma unroll
    for (int kt = 0; kt < KT; ++kt) {
        f16x8 ah = *(const f16x8*)(Ah + lrow * lda + kt * 32 + lk8);
        f16x8 al = *(const f16x8*)(Al + lrow * lda + kt * 32 + lk8);
        acc = MFMA(ah, bh[kt], acc);
        pe  = MFMA(ah, bl[kt], pe);
        qe  = MFMA(al, bh[kt], qe);
    }
    return acc + (pe + qe) * INV;
}

__global__ __launch_bounds__(512, 1) void odernn_mfma(
    const float* __restrict__ x2d, const int* __restrict__ maskp,
    const _Float16* __restrict__ w0h, const _Float16* __restrict__ w0l,
    const _Float16* __restrict__ w1hg, const _Float16* __restrict__ w1lg,
    const _Float16* __restrict__ w2h, const _Float16* __restrict__ w2l,
    const _Float16* __restrict__ hh0h, const _Float16* __restrict__ hh0l,
    const _Float16* __restrict__ ih1h, const _Float16* __restrict__ ih1l,
    const _Float16* __restrict__ hh1h, const _Float16* __restrict__ hh1l,
    const float* __restrict__ b0, const float* __restrict__ b1,
    const float* __restrict__ b2, const float* __restrict__ bhh0,
    const float* __restrict__ bih0, const float* __restrict__ wih0,
    const float* __restrict__ bih1, const float* __restrict__ bhh1,
    const float* __restrict__ wout, const float* __restrict__ bout,
    const float* __restrict__ h0, float* __restrict__ out)
{
    __shared__ float hF[16][128];                       // fp32 master hidden state
    __shared__ _Float16 bAh[16][264], bAl[16][264];     // t2 (256-wide) hi/lo
    __shared__ _Float16 bBh[16][264], bBl[16][264];     // t1 / h2 hi/lo
    __shared__ _Float16 bHh[16][136], bHl[16][136];     // current h / h1 hi/lo
    __shared__ float sbias[NBIAS];
    __shared__ float swi0[768];
    __shared__ float swout[384];
    __shared__ float sbout[4];
    __shared__ float sx0[16], sx1[16], smm[16];
    __shared__ int sIdx[16];

    const int tid = (int)threadIdx.x;
    const int wv = tid >> 6;            // wave 0..7
    const int l = tid & 63;
    const int lrow = l & 15;            // A-row / D-col within tile
    const int lk8 = (l >> 4) << 3;      // k-octet within 32-wide k-tile
    const int rbase = (l >> 4) << 2;    // D-row base for this lane

    // ---- LDS init ----
    for (int e = tid; e < 256; e += 512) { sbias[OB0 + e] = b0[e]; sbias[OB1 + e] = b1[e]; }
    for (int e = tid; e < 128; e += 512) sbias[OB2 + e] = b2[e];
    for (int e = tid; e < 384; e += 512) {
        sbias[OBHH0 + e] = bhh0[e];
        sbias[OBIH0 + e] = bih0[e];
        sbias[OBIH1 + e] = bih1[e];
        sbias[OBHH1 + e] = bhh1[e];
        swout[e] = wout[e];
    }
    for (int e = tid; e < 768; e += 512) swi0[e] = wih0[e];
    if (tid < 3) sbout[tid] = bout[tid];
    for (int e = tid; e < 2048; e += 512) {
        int row = e >> 7, col = e & 127;
        float v = h0[col];
        hF[row][col] = v;
        _Float16 hh = (_Float16)v;
        bHh[row][col] = hh;
        bHl[row][col] = (_Float16)((v - (float)hh) * LS);
    }
    if (tid < 16) {
        int grow = (int)blockIdx.x * 16 + tid;
        int bb = grow / 34, nn = grow - bb * 34;
        sIdx[tid] = bb * (S_ * 34) + nn;
    }
    __syncthreads();

    for (int s = 0; s < S_; ++s) {
        // x/mask for this step (consumed at P5, several barriers later)
        if (tid < 16) {
            int idx = sIdx[tid] + s * 34;
            float fm = (float)maskp[idx];
            smm[tid] = fm;
            sx0[tid] = x2d[2 * idx] * fm;
            sx1[tid] = x2d[2 * idx + 1] * fm;
        }

        // ================= 4 Euler steps =================
        for (int it = 0; it < 4; ++it) {
            // P1: t1 = tanh(h @ w0 + b0) -> bufB   (K=128 KT=4, 2 tiles/wave, sequential)
            {
                f32x4 v0 = tile_mm<4>(w0h, w0l, wv, &bHh[0][0], &bHl[0][0], 136,
                                      l, lrow, lk8, sbias[OB0 + (wv << 4) + lrow]);
                f32x4 v1 = tile_mm<4>(w0h, w0l, wv + 8, &bHh[0][0], &bHl[0][0], 136,
                                      l, lrow, lk8, sbias[OB0 + ((wv + 8) << 4) + lrow]);
                const int n0 = wv << 4, n1 = (wv + 8) << 4;
#pragma unroll
                for (int r = 0; r < 4; ++r) {
                    int row = rbase + r;
                    float t0 = fast_tanh(v0[r]);
                    float t1 = fast_tanh(v1[r]);
                    _Float16 hh = (_Float16)t0;
                    bBh[row][n0 + lrow] = hh;
                    bBl[row][n0 + lrow] = (_Float16)((t0 - (float)hh) * LS);
                    hh = (_Float16)t1;
                    bBh[row][n1 + lrow] = hh;
                    bBl[row][n1 + lrow] = (_Float16)((t1 - (float)hh) * LS);
                }
            }
            __syncthreads();

            // P2: t2 = tanh(t1 @ w1 + b1) -> bufA  (K=256 KT=8, 2 tiles/wave, sequential)
            {
                f32x4 v0 = tile_mm<8>(w1hg, w1lg, wv, &bBh[0][0], &bBl[0][0], 264,
                                      l, lrow, lk8, sbias[OB1 + (wv << 4) + lrow]);
                f32x4 v1 = tile_mm<8>(w1hg, w1lg, wv + 8, &bBh[0][0], &bBl[0][0], 264,
                                      l, lrow, lk8, sbias[OB1 + ((wv + 8) << 4) + lrow]);
                const int n0 = wv << 4, n1 = (wv + 8) << 4;
#pragma unroll
                for (int r = 0; r < 4; ++r) {
                    int row = rbase + r;
                    float t0 = fast_tanh(v0[r]);
                    float t1 = fast_tanh(v1[r]);
                    _Float16 hh = (_Float16)t0;
                    bAh[row][n0 + lrow] = hh;
                    bAl[row][n0 + lrow] = (_Float16)((t0 - (float)hh) * LS);
                    hh = (_Float16)t1;
                    bAh[row][n1 + lrow] = hh;
                    bAl[row][n1 + lrow] = (_Float16)((t1 - (float)hh) * LS);
                }
            }
            __syncthreads();

            // P3: f = t2 @ w2 + b2 ; hF += DT*f ; cast new h -> bufH  (KT=8, 1 tile/wave)
            {
                f32x4 f = tile_mm<8>(w2h, w2l, wv, &bAh[0][0], &bAl[0][0], 264,
                                     l, lrow, lk8, sbias[OB2 + (wv << 4) + lrow]);
#pragma unroll
                for (int r = 0; r < 4; ++r) {
                    int row = rbase + r, col = (wv << 4) + lrow;
                    float v = hF[row][col] + DT_ * f[r];
                    hF[row][col] = v;
                    _Float16 hh = (_Float16)v;
                    bHh[row][col] = hh;
                    bHl[row][col] = (_Float16)((v - (float)hh) * LS);
                }
            }
            __syncthreads();
        }

        // P5: gh0 = h1 @ whh0 + bhh0 (3 tiles/wave) ; y-out ; GRU0 combine -> bufB
        {
            f32x4 gh[3];
#pragma unroll
            for (int t = 0; t < 3; ++t)
                gh[t] = tile_mm<4>(hh0h, hh0l, wv + (t << 3), &bHh[0][0], &bHl[0][0], 136,
                                   l, lrow, lk8, sbias[OBHH0 + ((wv + (t << 3)) << 4) + lrow]);
            // y = h1 @ wout + bout  (lanes 0-31: row wv ; lanes 32-63: row wv+8)
            {
                int yrow = wv + ((l >> 5) << 3);
                int ll = l & 31;
                int c0 = ll << 2;
                float4 hv = *(const float4*)&hF[yrow][c0];
                float y0 = hv.x * swout[c0 * 3] + hv.y * swout[(c0 + 1) * 3] +
                           hv.z * swout[(c0 + 2) * 3] + hv.w * swout[(c0 + 3) * 3];
                float y1 = hv.x * swout[c0 * 3 + 1] + hv.y * swout[(c0 + 1) * 3 + 1] +
                           hv.z * swout[(c0 + 2) * 3 + 1] + hv.w * swout[(c0 + 3) * 3 + 1];
                float y2 = hv.x * swout[c0 * 3 + 2] + hv.y * swout[(c0 + 1) * 3 + 2] +
                           hv.z * swout[(c0 + 2) * 3 + 2] + hv.w * swout[(c0 + 3) * 3 + 2];
#pragma unroll
                for (int m = 16; m >= 1; m >>= 1) {
                    y0 += __shfl_xor(y0, m, 64);
                    y1 += __shfl_xor(y1, m, 64);
                    y2 += __shfl_xor(y2, m, 64);
                }
                if (ll == 0) {
                    int idx = sIdx[yrow] + s * 34;
                    out[idx * 3 + 0] = y0 + sbout[0];
                    out[idx * 3 + 1] = y1 + sbout[1];
                    out[idx * 3 + 2] = y2 + sbout[2];
                }
            }
            // GRU0 combine: h2 -> bufB cols 0..127
            {
                int col = (wv << 4) + lrow;
                float wxr0 = swi0[col], wxr1 = swi0[384 + col];
                float wxz0 = swi0[128 + col], wxz1 = swi0[384 + 128 + col];
                float wxn0 = swi0[256 + col], wxn1 = swi0[384 + 256 + col];
                float bir = sbias[OBIH0 + col], biz = sbias[OBIH0 + 128 + col], bin = sbias[OBIH0 + 256 + col];
#pragma unroll
                for (int r = 0; r < 4; ++r) {
                    int row = rbase + r;
                    float xa = sx0[row], xb = sx1[row];
                    float rg = fast_sigmoid(bir + xa * wxr0 + xb * wxr1 + gh[0][r]);
                    float zg = fast_sigmoid(biz + xa * wxz0 + xb * wxz1 + gh[1][r]);
                    float nn = fast_tanh(bin + xa * wxn0 + xb * wxn1 + rg * gh[2][r]);
                    float h1 = hF[row][col];
                    float h2 = (1.0f - zg) * nn + zg * h1;
                    _Float16 hh = (_Float16)h2;
                    bBh[row][col] = hh;
                    bBl[row][col] = (_Float16)((h2 - (float)hh) * LS);
                }
            }
        }
        __syncthreads();

        // P7: gi1 = h2 @ wih1 + bih1 ; gh1 = h1 @ whh1 + bhh1 ; GRU1 combine -> hF + bufH
        {
            f32x4 gi[3], gh[3];
#pragma unroll
            for (int t = 0; t < 3; ++t)
                gi[t] = tile_mm<4>(ih1h, ih1l, wv + (t << 3), &bBh[0][0], &bBl[0][0], 264,
                                   l, lrow, lk8, sbias[OBIH1 + ((wv + (t << 3)) << 4) + lrow]);
#pragma unroll
            for (int t = 0; t < 3; ++t)
                gh[t] = tile_mm<4>(hh1h, hh1l, wv + (t << 3), &bHh[0][0], &bHl[0][0], 136,
                                   l, lrow, lk8, sbias[OBHH1 + ((wv + (t << 3)) << 4) + lrow]);

            __syncthreads();   // all reads of bHh/bHl/bBh for this step are done
#pragma unroll
            for (int r = 0; r < 4; ++r) {
                int row = rbase + r, col = (wv << 4) + lrow;
                float rg = fast_sigmoid(gi[0][r] + gh[0][r]);
                float zg = fast_sigmoid(gi[1][r] + gh[1][r]);
                float nn = fast_tanh(gi[2][r] + rg * gh[2][r]);
                float h1 = hF[row][col];
                float h2 = (1.0f - zg) * nn + zg * h1;
                float v = (smm[row] != 0.0f) ? h2 : h1;
                hF[row][col] = v;
                _Float16 hh = (_Float16)v;
                bHh[row][col] = hh;
                bHl[row][col] = (_Float16)((v - (float)hh) * LS);
            }
        }
        __syncthreads();
    }
}

extern "C" void kernel_launch(void* const* d_in, const int* in_sizes, int n_in,
                              void* d_out, int out_size, void* d_ws, size_t ws_size,
                              hipStream_t stream) {
    const float* x2d  = (const float*)d_in[0];
    const int*   mask = (const int*)d_in[1];
    const float* w0   = (const float*)d_in[2];
    const float* b0   = (const float*)d_in[3];
    const float* w1   = (const float*)d_in[4];
    const float* b1   = (const float*)d_in[5];
    const float* w2   = (const float*)d_in[6];
    const float* b2   = (const float*)d_in[7];
    const float* wih0 = (const float*)d_in[8];
    const float* whh0 = (const float*)d_in[9];
    const float* bih0 = (const float*)d_in[10];
    const float* bhh0 = (const float*)d_in[11];
    const float* wih1 = (const float*)d_in[12];
    const float* whh1 = (const float*)d_in[13];
    const float* bih1 = (const float*)d_in[14];
    const float* bhh1 = (const float*)d_in[15];
    const float* wout = (const float*)d_in[16];
    const float* bout = (const float*)d_in[17];
    const float* h0   = (const float*)d_in[18];
    float* out = (float*)d_out;

    _Float16* base = (_Float16*)d_ws;
    _Float16* pw0h  = base;                 // 32768
    _Float16* pw1h  = base + 32768;         // 65536
    _Float16* pw2h  = base + 98304;         // 32768
    _Float16* ph0h  = base + 131072;        // 49152 (whh0)
    _Float16* pi1h  = base + 180224;        // 49152 (wih1)
    _Float16* ph1h  = base + 229376;        // 49152 (whh1)
    _Float16* lobase = base + 278528;
    _Float16* pw0l  = lobase;
    _Float16* pw1l  = lobase + 32768;
    _Float16* pw2l  = lobase + 98304;
    _Float16* ph0l  = lobase + 131072;
    _Float16* pi1l  = lobase + 180224;
    _Float16* ph1l  = lobase + 229376;

    hipLaunchKernelGGL(prep_hl, dim3(128), dim3(256), 0, stream, w0,   pw0h, pw0l, 128, 256);
    hipLaunchKernelGGL(prep_hl, dim3(256), dim3(256), 0, stream, w1,   pw1h, pw1l, 256, 256);
    hipLaunchKernelGGL(prep_hl, dim3(128), dim3(256), 0, stream, w2,   pw2h, pw2l, 256, 128);
    hipLaunchKernelGGL(prep_hl, dim3(192), dim3(256), 0, stream, whh0, ph0h, ph0l, 128, 384);
    hipLaunchKernelGGL(prep_hl, dim3(192), dim3(256), 0, stream, wih1, pi1h, pi1l, 128, 384);
    hipLaunchKernelGGL(prep_hl, dim3(192), dim3(256), 0, stream, whh1, ph1h, ph1l, 128, 384);

    hipLaunchKernelGGL(odernn_mfma, dim3(68), dim3(512), 0, stream,
        x2d, mask, pw0h, pw0l, pw1h, pw1l, pw2h, pw2l,
        ph0h, ph0l, pi1h, pi1l, ph1h, ph1l,
        b0, b1, b2, bhh0, bih0, wih0, bih1, bhh1, wout, bout, h0, out);
}